// Round 17
// baseline (147.287 us; speedup 1.0000x reference)
//
#include <hip/hip_runtime.h>
#include <hip/hip_bf16.h>

#define SEQ 2048
#define DM  1024
#define NH  16
#define HD  64
#define BH  32
#define QB  64            // q rows per block; 4 waves = (q-half x kv-half)
#define KVB 64
#define NT  (SEQ/KVB)     // 32 tiles

#define KWS_OFF 0u        // [BH][NT][kvh][st][64 lane][8]     K fragment-linear (bf16)
#define VWS_OFF 4194304u  // [BH][NT][kvh][db][ks][64 lane][8] V fragment-linear (f16)

typedef __bf16    bf16x8 __attribute__((ext_vector_type(8)));
typedef _Float16  f16x8  __attribute__((ext_vector_type(8)));
typedef float     f32x16 __attribute__((ext_vector_type(16)));
typedef unsigned int u32;

// ---- prep: K bf16 frag-linear; V f16 frag-linear ----
__global__ __launch_bounds__(256) void psa_prep(
    const float* __restrict__ V, const float* __restrict__ K,
    __bf16* __restrict__ ws)
{
    const int blk = blockIdx.x;
    if (blk < 2048) {
        // K frag chunk (bh, t, kvh, st, lane):
        // elem j = K[b][t*64 + kvh*32 + (lane&31)][h*64 + st*16 + (lane>>5)*8 + j]
        const int idx = blk * 256 + threadIdx.x;
        const int lane = idx & 63, st = (idx >> 6) & 3;
        const int kvh = (idx >> 8) & 1, t = (idx >> 9) & 31, bh = idx >> 14;
        const int b = bh >> 4, h = bh & 15;
        const int row = t * 64 + kvh * 32 + (lane & 31);
        const int d0  = st * 16 + (lane >> 5) * 8;
        const float* src = K + ((size_t)(b * SEQ + row)) * DM + h * HD + d0;
        float4 a = *(const float4*)src, c = *(const float4*)(src + 4);
        bf16x8 o;
        o[0] = (__bf16)a.x; o[1] = (__bf16)a.y; o[2] = (__bf16)a.z; o[3] = (__bf16)a.w;
        o[4] = (__bf16)c.x; o[5] = (__bf16)c.y; o[6] = (__bf16)c.z; o[7] = (__bf16)c.w;
        *(bf16x8*)(ws + KWS_OFF + (size_t)idx * 8) = o;
    } else {
        // V frag chunk (bh, t, kvh, db, ks, lane), stored f16:
        // elem j = V[b][t*64 + kvh*32 + ks*16 + (lane>>5)*8 + j][h*64 + db*32 + (lane&31)]
        const int idx = (blk - 2048) * 256 + threadIdx.x;
        const int lane = idx & 63, ks = (idx >> 6) & 1, db = (idx >> 7) & 1;
        const int kvh = (idx >> 8) & 1, t = (idx >> 9) & 31, bh = idx >> 14;
        const int b = bh >> 4, h = bh & 15;
        const int key0 = t * 64 + kvh * 32 + ks * 16 + (lane >> 5) * 8;
        const int col  = h * HD + db * 32 + (lane & 31);
        const float* src = V + (size_t)(b * SEQ + key0) * DM + col;
        f16x8 o;
#pragma unroll
        for (int j = 0; j < 8; ++j) o[j] = (_Float16)src[(size_t)j * DM];
        *(f16x8*)(ws + VWS_OFF + (size_t)idx * 8) = o;
    }
}

// ---- main: zero barriers; K,V direct global->reg both double-buffered 1 tile ahead;
//      QK split into 2 independent chains; packed-f16 trans-free silu; f16 PV ----
__global__ __launch_bounds__(256, 4) void psa_main(
    const __bf16* __restrict__ ws, const float* __restrict__ Qg,
    float* __restrict__ Og)
{
    __shared__ float red[32 * 128];       // epilogue reduction only (16 KB)

    const int bid = blockIdx.x;
    const int swz = (bid & 7) * 128 + (bid >> 3);   // XCD-aware; 1024 % 8 == 0
    const int bh  = swz >> 5;
    const int qb  = swz & 31;
    const int b   = bh >> 4, h = bh & 15;
    const int tid = threadIdx.x;
    const int w   = tid >> 6;
    const int l   = tid & 63;
    const int q32 = l & 31;
    const int hi  = l >> 5;
    const int qh  = w & 1;                // q-half
    const int kvh = w >> 1;               // kv-half
    const int q0  = qb * QB + qh * 32;

    const __bf16* kbase = ws + KWS_OFF + (size_t)bh * 131072 + kvh * 2048 + l * 8;
    const __bf16* vbase = ws + VWS_OFF + (size_t)bh * 131072 + kvh * 2048 + l * 8;

    // packed-f16 silu constants
    const u32 c_n4   = 0xC400C400u;   // -4.0 x2
    const u32 c_p4   = 0x44004400u;   // +4.0 x2
    const u32 c_mask = 0x7FFF7FFFu;   // |.| x2
    u32 c_a;                          // -0.03125 x2 (VGPR)
    asm("v_mov_b32 %0, 0xA800A800" : "=v"(c_a));
    const u32 c_b    = 0x34003400u;   // 0.25 x2
    const u32 c_h    = 0x38003800u;   // 0.5  x2

    // Q B-frags: lane holds col q = q0+q32, k-dim d = st*16 + hi*8 + j
    bf16x8 qf[4];
#pragma unroll
    for (int st = 0; st < 4; ++st) {
        const float* p = Qg + ((size_t)b * SEQ + q0 + q32) * DM + h * HD + st * 16 + hi * 8;
        float4 a = *(const float4*)p, c = *(const float4*)(p + 4);
        bf16x8 o;
        o[0] = (__bf16)a.x; o[1] = (__bf16)a.y; o[2] = (__bf16)a.z; o[3] = (__bf16)a.w;
        o[4] = (__bf16)c.x; o[5] = (__bf16)c.y; o[6] = (__bf16)c.z; o[7] = (__bf16)c.w;
        qf[st] = o;
    }

    f32x16 accd[2], z16;
#pragma unroll
    for (int r = 0; r < 16; ++r) { accd[0][r] = 0.f; accd[1][r] = 0.f; z16[r] = 0.f; }

    auto tile = [&](int t, bf16x8 (&kCur)[4], bf16x8 (&kNxt)[4],
                    f16x8 (&vCur)[4], f16x8 (&vNxt)[4]) {
        // prefetch tile t+1 (K and V) — consumed next body, full tile of latency
        if (t + 1 < NT) {
#pragma unroll
            for (int st = 0; st < 4; ++st)
                kNxt[st] = *(const bf16x8*)(kbase + (size_t)(t + 1) * 4096 + st * 512);
#pragma unroll
            for (int j = 0; j < 4; ++j)
                vNxt[j] = *(const f16x8*)(vbase + (size_t)(t + 1) * 4096 + j * 512);
        }

        // ---- QK^T: two independent 2-deep chains, then packed merge
        __builtin_amdgcn_s_setprio(1);
        f32x16 sa = __builtin_amdgcn_mfma_f32_32x32x16_bf16(kCur[0], qf[0], z16, 0, 0, 0);
        f32x16 sb = __builtin_amdgcn_mfma_f32_32x32x16_bf16(kCur[1], qf[1], z16, 0, 0, 0);
        sa = __builtin_amdgcn_mfma_f32_32x32x16_bf16(kCur[2], qf[2], sa, 0, 0, 0);
        sb = __builtin_amdgcn_mfma_f32_32x32x16_bf16(kCur[3], qf[3], sb, 0, 0, 0);
        __builtin_amdgcn_s_setprio(0);
        f32x16 s = sa + sb;                      // v_pk_add_f32 x8

        // ---- silu, packed f16: xc=clamp(x,-4,4); p=0.5+xc*(0.25-0.03125*|xc|); y=x*p
        u32 pw[2][4];
#pragma unroll
        for (int hf = 0; hf < 2; ++hf) {
            u32 Y[4];
#pragma unroll
            for (int pr = 0; pr < 4; ++pr) {
                u32 xpk = __builtin_bit_cast(
                    u32, __builtin_amdgcn_cvt_pkrtz(s[hf * 8 + 2 * pr], s[hf * 8 + 2 * pr + 1]));
                u32 t1, xc, ax, u, p, y;
                asm("v_pk_max_f16 %0, %1, %2" : "=v"(t1) : "v"(xpk), "s"(c_n4));
                asm("v_pk_min_f16 %0, %1, %2" : "=v"(xc) : "v"(t1), "s"(c_p4));
                asm("v_and_b32 %0, %1, %2"    : "=v"(ax) : "s"(c_mask), "v"(xc));
                asm("v_pk_fma_f16 %0, %1, %2, %3" : "=v"(u) : "v"(ax), "v"(c_a), "s"(c_b));
                asm("v_pk_fma_f16 %0, %1, %2, %3" : "=v"(p) : "v"(xc), "v"(u), "s"(c_h));
                asm("v_pk_mul_f16 %0, %1, %2" : "=v"(y) : "v"(xpk), "v"(p));
                Y[pr] = y;
            }
            asm("v_permlane32_swap_b32 %0, %1" : "+v"(Y[0]), "+v"(Y[2]));
            asm("v_permlane32_swap_b32 %0, %1" : "+v"(Y[1]), "+v"(Y[3]));
            pw[hf][0] = Y[0]; pw[hf][1] = Y[1]; pw[hf][2] = Y[2]; pw[hf][3] = Y[3];
        }

        // ---- out += P * V  (interleaved: adjacent MFMAs independent)
        union { u32 u[4]; f16x8 v; } p0, p1;
        p0.u[0] = pw[0][0]; p0.u[1] = pw[0][1]; p0.u[2] = pw[0][2]; p0.u[3] = pw[0][3];
        p1.u[0] = pw[1][0]; p1.u[1] = pw[1][1]; p1.u[2] = pw[1][2]; p1.u[3] = pw[1][3];
        __builtin_amdgcn_s_setprio(1);
        accd[0] = __builtin_amdgcn_mfma_f32_32x32x16_f16(p0.v, vCur[0], accd[0], 0, 0, 0);
        accd[1] = __builtin_amdgcn_mfma_f32_32x32x16_f16(p0.v, vCur[2], accd[1], 0, 0, 0);
        accd[0] = __builtin_amdgcn_mfma_f32_32x32x16_f16(p1.v, vCur[1], accd[0], 0, 0, 0);
        accd[1] = __builtin_amdgcn_mfma_f32_32x32x16_f16(p1.v, vCur[3], accd[1], 0, 0, 0);
        __builtin_amdgcn_s_setprio(0);
    };

    bf16x8 kA[4], kB[4];
    f16x8  vA[4], vB[4];
#pragma unroll
    for (int st = 0; st < 4; ++st)
        kA[st] = *(const bf16x8*)(kbase + st * 512);
#pragma unroll
    for (int j = 0; j < 4; ++j)
        vA[j] = *(const f16x8*)(vbase + j * 512);

    for (int t = 0; t < NT; t += 2) {
        tile(t,     kA, kB, vA, vB);
        tile(t + 1, kB, kA, vB, vA);
    }

    // ---- kv-half reduction via LDS (lane-contiguous, conflict-free)
    if (w >= 2) {                                    // kvh==1 writes
#pragma unroll
        for (int db = 0; db < 2; ++db)
#pragma unroll
            for (int r = 0; r < 16; ++r)
                red[(db * 16 + r) * 128 + qh * 64 + l] = accd[db][r];
    }
    __syncthreads();
    if (w < 2) {                                     // kvh==0 adds + stores
#pragma unroll
        for (int db = 0; db < 2; ++db)
#pragma unroll
            for (int r = 0; r < 16; ++r)
                accd[db][r] += red[(db * 16 + r) * 128 + qh * 64 + l];
        // D layout: row q = m*8 + r + hi*4, col d = db*32 + q32 (coalesced)
        float* op = Og + ((size_t)b * SEQ + q0) * DM + h * HD;
#pragma unroll
        for (int db = 0; db < 2; ++db)
#pragma unroll
            for (int m = 0; m < 4; ++m)
#pragma unroll
                for (int r = 0; r < 4; ++r)
                    op[(size_t)(m * 8 + r + hi * 4) * DM + db * 32 + q32] = accd[db][m * 4 + r];
    }
}

extern "C" void kernel_launch(void* const* d_in, const int* in_sizes, int n_in,
                              void* d_out, int out_size, void* d_ws, size_t ws_size,
                              hipStream_t stream) {
    const float* v = (const float*)d_in[0];
    const float* k = (const float*)d_in[1];
    const float* q = (const float*)d_in[2];
    float* out = (float*)d_out;
    __bf16* ws = (__bf16*)d_ws;
    (void)in_sizes; (void)n_in; (void)out_size; (void)ws_size;

    psa_prep<<<dim3(4096), dim3(256), 0, stream>>>(v, k, ws);
    psa_main<<<dim3(BH * (SEQ / QB)), dim3(256), 0, stream>>>(ws, q, out);
}

// Round 18
// 87.007 us; speedup vs baseline: 1.6928x; 1.6928x over previous
//
#include <hip/hip_runtime.h>
#include <hip/hip_bf16.h>

#define SEQ 2048
#define DM  1024
#define NH  16
#define HD  64
#define BH  32
#define QB  64            // q rows per block; 4 waves = (q-half x kv-half)
#define KVB 64
#define NT  (SEQ/KVB)     // 32 tiles

#define KWS_OFF 0u        // [BH][NT][kvh][st][64 lane][8]     K fragment-linear (bf16)
#define VWS_OFF 4194304u  // [BH][NT][kvh][db][ks][64 lane][8] V fragment-linear (f16)

typedef __bf16    bf16x8 __attribute__((ext_vector_type(8)));
typedef _Float16  f16x8  __attribute__((ext_vector_type(8)));
typedef float     f32x16 __attribute__((ext_vector_type(16)));
typedef unsigned int u32;

// ---- prep: K bf16 frag-linear; V f16 frag-linear ----
__global__ __launch_bounds__(256) void psa_prep(
    const float* __restrict__ V, const float* __restrict__ K,
    __bf16* __restrict__ ws)
{
    const int blk = blockIdx.x;
    if (blk < 2048) {
        // K frag chunk (bh, t, kvh, st, lane):
        // elem j = K[b][t*64 + kvh*32 + (lane&31)][h*64 + st*16 + (lane>>5)*8 + j]
        const int idx = blk * 256 + threadIdx.x;
        const int lane = idx & 63, st = (idx >> 6) & 3;
        const int kvh = (idx >> 8) & 1, t = (idx >> 9) & 31, bh = idx >> 14;
        const int b = bh >> 4, h = bh & 15;
        const int row = t * 64 + kvh * 32 + (lane & 31);
        const int d0  = st * 16 + (lane >> 5) * 8;
        const float* src = K + ((size_t)(b * SEQ + row)) * DM + h * HD + d0;
        float4 a = *(const float4*)src, c = *(const float4*)(src + 4);
        bf16x8 o;
        o[0] = (__bf16)a.x; o[1] = (__bf16)a.y; o[2] = (__bf16)a.z; o[3] = (__bf16)a.w;
        o[4] = (__bf16)c.x; o[5] = (__bf16)c.y; o[6] = (__bf16)c.z; o[7] = (__bf16)c.w;
        *(bf16x8*)(ws + KWS_OFF + (size_t)idx * 8) = o;
    } else {
        // V frag chunk (bh, t, kvh, db, ks, lane), stored f16:
        // elem j = V[b][t*64 + kvh*32 + ks*16 + (lane>>5)*8 + j][h*64 + db*32 + (lane&31)]
        const int idx = (blk - 2048) * 256 + threadIdx.x;
        const int lane = idx & 63, ks = (idx >> 6) & 1, db = (idx >> 7) & 1;
        const int kvh = (idx >> 8) & 1, t = (idx >> 9) & 31, bh = idx >> 14;
        const int b = bh >> 4, h = bh & 15;
        const int key0 = t * 64 + kvh * 32 + ks * 16 + (lane >> 5) * 8;
        const int col  = h * HD + db * 32 + (lane & 31);
        const float* src = V + (size_t)(b * SEQ + key0) * DM + col;
        f16x8 o;
#pragma unroll
        for (int j = 0; j < 8; ++j) o[j] = (_Float16)src[(size_t)j * DM];
        *(f16x8*)(ws + VWS_OFF + (size_t)idx * 8) = o;
    }
}

// ---- main: zero barriers in loop; K,V direct global->reg, BOTH prefetched
//      one tile ahead; packed-f16 trans-free silu; PV in f16 MFMA ----
__global__ __launch_bounds__(256, 4) void psa_main(
    const __bf16* __restrict__ ws, const float* __restrict__ Qg,
    float* __restrict__ Og)
{
    __shared__ float red[32 * 128];       // epilogue reduction only (16 KB)

    const int bid = blockIdx.x;
    const int swz = (bid & 7) * 128 + (bid >> 3);   // XCD-aware; 1024 % 8 == 0
    const int bh  = swz >> 5;
    const int qb  = swz & 31;
    const int b   = bh >> 4, h = bh & 15;
    const int tid = threadIdx.x;
    const int w   = tid >> 6;
    const int l   = tid & 63;
    const int q32 = l & 31;
    const int hi  = l >> 5;
    const int qh  = w & 1;                // q-half
    const int kvh = w >> 1;               // kv-half
    const int q0  = qb * QB + qh * 32;

    const __bf16* kbase = ws + KWS_OFF + (size_t)bh * 131072 + kvh * 2048 + l * 8;
    const __bf16* vbase = ws + VWS_OFF + (size_t)bh * 131072 + kvh * 2048 + l * 8;

    // packed-f16 silu constants (SGPR/VGPR per <=1-SGPR-read rule)
    const u32 c_n4   = 0xC400C400u;   // -4.0 x2
    const u32 c_p4   = 0x44004400u;   // +4.0 x2
    const u32 c_mask = 0x7FFF7FFFu;   // |.| x2
    u32 c_a;                          // -0.03125 x2 (VGPR)
    asm("v_mov_b32 %0, 0xA800A800" : "=v"(c_a));
    const u32 c_b    = 0x34003400u;   // 0.25 x2
    const u32 c_h    = 0x38003800u;   // 0.5  x2

    // Q B-frags: lane holds col q = q0+q32, k-dim d = st*16 + hi*8 + j
    bf16x8 qf[4];
#pragma unroll
    for (int st = 0; st < 4; ++st) {
        const float* p = Qg + ((size_t)b * SEQ + q0 + q32) * DM + h * HD + st * 16 + hi * 8;
        float4 a = *(const float4*)p, c = *(const float4*)(p + 4);
        bf16x8 o;
        o[0] = (__bf16)a.x; o[1] = (__bf16)a.y; o[2] = (__bf16)a.z; o[3] = (__bf16)a.w;
        o[4] = (__bf16)c.x; o[5] = (__bf16)c.y; o[6] = (__bf16)c.z; o[7] = (__bf16)c.w;
        qf[st] = o;
    }

    f32x16 accd[2], z16;
#pragma unroll
    for (int r = 0; r < 16; ++r) { accd[0][r] = 0.f; accd[1][r] = 0.f; z16[r] = 0.f; }

    auto tile = [&](int t, bf16x8 (&kCur)[4], bf16x8 (&kNxt)[4],
                    f16x8 (&vCur)[4], f16x8 (&vNxt)[4]) {
        // prefetch tile t+1 (K and V) — consumed next body: full tile of latency
        if (t + 1 < NT) {
#pragma unroll
            for (int st = 0; st < 4; ++st)
                kNxt[st] = *(const bf16x8*)(kbase + (size_t)(t + 1) * 4096 + st * 512);
#pragma unroll
            for (int j = 0; j < 4; ++j)
                vNxt[j] = *(const f16x8*)(vbase + (size_t)(t + 1) * 4096 + j * 512);
        }

        // ---- QK^T (A=K half, B=Q) — serial chain (r16 form; no extra live acc)
        __builtin_amdgcn_s_setprio(1);
        f32x16 s = __builtin_amdgcn_mfma_f32_32x32x16_bf16(kCur[0], qf[0], z16, 0, 0, 0);
        s = __builtin_amdgcn_mfma_f32_32x32x16_bf16(kCur[1], qf[1], s, 0, 0, 0);
        s = __builtin_amdgcn_mfma_f32_32x32x16_bf16(kCur[2], qf[2], s, 0, 0, 0);
        s = __builtin_amdgcn_mfma_f32_32x32x16_bf16(kCur[3], qf[3], s, 0, 0, 0);
        __builtin_amdgcn_s_setprio(0);

        // ---- silu, packed f16: xc=clamp(x,-4,4); p=0.5+xc*(0.25-0.03125*|xc|); y=x*p
        u32 pw[2][4];
#pragma unroll
        for (int hf = 0; hf < 2; ++hf) {
            u32 Y[4];
#pragma unroll
            for (int pr = 0; pr < 4; ++pr) {
                u32 xpk = __builtin_bit_cast(
                    u32, __builtin_amdgcn_cvt_pkrtz(s[hf * 8 + 2 * pr], s[hf * 8 + 2 * pr + 1]));
                u32 t1, xc, ax, u, p, y;
                asm("v_pk_max_f16 %0, %1, %2" : "=v"(t1) : "v"(xpk), "s"(c_n4));
                asm("v_pk_min_f16 %0, %1, %2" : "=v"(xc) : "v"(t1), "s"(c_p4));
                asm("v_and_b32 %0, %1, %2"    : "=v"(ax) : "s"(c_mask), "v"(xc));
                asm("v_pk_fma_f16 %0, %1, %2, %3" : "=v"(u) : "v"(ax), "v"(c_a), "s"(c_b));
                asm("v_pk_fma_f16 %0, %1, %2, %3" : "=v"(p) : "v"(xc), "v"(u), "s"(c_h));
                asm("v_pk_mul_f16 %0, %1, %2" : "=v"(y) : "v"(xpk), "v"(p));
                Y[pr] = y;
            }
            asm("v_permlane32_swap_b32 %0, %1" : "+v"(Y[0]), "+v"(Y[2]));
            asm("v_permlane32_swap_b32 %0, %1" : "+v"(Y[1]), "+v"(Y[3]));
            pw[hf][0] = Y[0]; pw[hf][1] = Y[1]; pw[hf][2] = Y[2]; pw[hf][3] = Y[3];
        }

        // ---- out += P * V   (f16 MFMA; V from prefetched regs)
        union { u32 u[4]; f16x8 v; } p0, p1;
        p0.u[0] = pw[0][0]; p0.u[1] = pw[0][1]; p0.u[2] = pw[0][2]; p0.u[3] = pw[0][3];
        p1.u[0] = pw[1][0]; p1.u[1] = pw[1][1]; p1.u[2] = pw[1][2]; p1.u[3] = pw[1][3];
        __builtin_amdgcn_s_setprio(1);
        accd[0] = __builtin_amdgcn_mfma_f32_32x32x16_f16(p0.v, vCur[0], accd[0], 0, 0, 0);
        accd[1] = __builtin_amdgcn_mfma_f32_32x32x16_f16(p0.v, vCur[2], accd[1], 0, 0, 0);
        accd[0] = __builtin_amdgcn_mfma_f32_32x32x16_f16(p1.v, vCur[1], accd[0], 0, 0, 0);
        accd[1] = __builtin_amdgcn_mfma_f32_32x32x16_f16(p1.v, vCur[3], accd[1], 0, 0, 0);
        __builtin_amdgcn_s_setprio(0);
    };

    bf16x8 kA[4], kB[4];
    f16x8  vA[4], vB[4];
#pragma unroll
    for (int st = 0; st < 4; ++st)
        kA[st] = *(const bf16x8*)(kbase + st * 512);
#pragma unroll
    for (int j = 0; j < 4; ++j)
        vA[j] = *(const f16x8*)(vbase + j * 512);

    for (int t = 0; t < NT; t += 2) {
        tile(t,     kA, kB, vA, vB);
        tile(t + 1, kB, kA, vB, vA);
    }

    // ---- kv-half reduction via LDS (lane-contiguous, conflict-free)
    if (w >= 2) {                                    // kvh==1 writes
#pragma unroll
        for (int db = 0; db < 2; ++db)
#pragma unroll
            for (int r = 0; r < 16; ++r)
                red[(db * 16 + r) * 128 + qh * 64 + l] = accd[db][r];
    }
    __syncthreads();
    if (w < 2) {                                     // kvh==0 adds + stores
#pragma unroll
        for (int db = 0; db < 2; ++db)
#pragma unroll
            for (int r = 0; r < 16; ++r)
                accd[db][r] += red[(db * 16 + r) * 128 + qh * 64 + l];
        // D layout: row q = m*8 + r + hi*4, col d = db*32 + q32 (coalesced)
        float* op = Og + ((size_t)b * SEQ + q0) * DM + h * HD;
#pragma unroll
        for (int db = 0; db < 2; ++db)
#pragma unroll
            for (int m = 0; m < 4; ++m)
#pragma unroll
                for (int r = 0; r < 4; ++r)
                    op[(size_t)(m * 8 + r + hi * 4) * DM + db * 32 + q32] = accd[db][m * 4 + r];
    }
}

extern "C" void kernel_launch(void* const* d_in, const int* in_sizes, int n_in,
                              void* d_out, int out_size, void* d_ws, size_t ws_size,
                              hipStream_t stream) {
    const float* v = (const float*)d_in[0];
    const float* k = (const float*)d_in[1];
    const float* q = (const float*)d_in[2];
    float* out = (float*)d_out;
    __bf16* ws = (__bf16*)d_ws;
    (void)in_sizes; (void)n_in; (void)out_size; (void)ws_size;

    psa_prep<<<dim3(4096), dim3(256), 0, stream>>>(v, k, ws);
    psa_main<<<dim3(BH * (SEQ / QB)), dim3(256), 0, stream>>>(ws, q, out);
}

// Round 19
// 64.121 us; speedup vs baseline: 2.2970x; 1.3569x over previous
//
#include <hip/hip_runtime.h>
#include <hip/hip_bf16.h>

#define SEQ 2048
#define DM  1024
#define NH  16
#define HD  64
#define BH  32
#define QB  64            // q rows per block; 4 waves = (q-half x kv-half)
#define KVB 64
#define NT  (SEQ/KVB)     // 32 tiles

#define KWS_OFF 0u        // [BH][NT][kvh][st][64 lane][8]     K fragment-linear (bf16)
#define VWS_OFF 4194304u  // [BH][NT][kvh][db][ks][64 lane][8] V fragment-linear (f16)

typedef __bf16    bf16x8 __attribute__((ext_vector_type(8)));
typedef _Float16  f16x8  __attribute__((ext_vector_type(8)));
typedef float     f32x16 __attribute__((ext_vector_type(16)));
typedef unsigned int u32;

// ---- prep: K bf16 frag-linear; V f16 frag-linear ----
__global__ __launch_bounds__(256) void psa_prep(
    const float* __restrict__ V, const float* __restrict__ K,
    __bf16* __restrict__ ws)
{
    const int blk = blockIdx.x;
    if (blk < 2048) {
        // K frag chunk (bh, t, kvh, st, lane):
        // elem j = K[b][t*64 + kvh*32 + (lane&31)][h*64 + st*16 + (lane>>5)*8 + j]
        const int idx = blk * 256 + threadIdx.x;
        const int lane = idx & 63, st = (idx >> 6) & 3;
        const int kvh = (idx >> 8) & 1, t = (idx >> 9) & 31, bh = idx >> 14;
        const int b = bh >> 4, h = bh & 15;
        const int row = t * 64 + kvh * 32 + (lane & 31);
        const int d0  = st * 16 + (lane >> 5) * 8;
        const float* src = K + ((size_t)(b * SEQ + row)) * DM + h * HD + d0;
        float4 a = *(const float4*)src, c = *(const float4*)(src + 4);
        bf16x8 o;
        o[0] = (__bf16)a.x; o[1] = (__bf16)a.y; o[2] = (__bf16)a.z; o[3] = (__bf16)a.w;
        o[4] = (__bf16)c.x; o[5] = (__bf16)c.y; o[6] = (__bf16)c.z; o[7] = (__bf16)c.w;
        *(bf16x8*)(ws + KWS_OFF + (size_t)idx * 8) = o;
    } else {
        // V frag chunk (bh, t, kvh, db, ks, lane), stored f16:
        // elem j = V[b][t*64 + kvh*32 + ks*16 + (lane>>5)*8 + j][h*64 + db*32 + (lane&31)]
        const int idx = (blk - 2048) * 256 + threadIdx.x;
        const int lane = idx & 63, ks = (idx >> 6) & 1, db = (idx >> 7) & 1;
        const int kvh = (idx >> 8) & 1, t = (idx >> 9) & 31, bh = idx >> 14;
        const int b = bh >> 4, h = bh & 15;
        const int key0 = t * 64 + kvh * 32 + ks * 16 + (lane >> 5) * 8;
        const int col  = h * HD + db * 32 + (lane & 31);
        const float* src = V + (size_t)(b * SEQ + key0) * DM + col;
        f16x8 o;
#pragma unroll
        for (int j = 0; j < 8; ++j) o[j] = (_Float16)src[(size_t)j * DM];
        *(f16x8*)(ws + VWS_OFF + (size_t)idx * 8) = o;
    }
}

// ---- main: zero barriers in loop; K,V direct global->reg;
//      packed-f16 trans-free silu; PV in f16 MFMA ----
__global__ __launch_bounds__(256, 4) void psa_main(
    const __bf16* __restrict__ ws, const float* __restrict__ Qg,
    float* __restrict__ Og)
{
    __shared__ float red[32 * 128];       // epilogue reduction only (16 KB)

    const int bid = blockIdx.x;
    const int swz = (bid & 7) * 128 + (bid >> 3);   // XCD-aware; 1024 % 8 == 0
    const int bh  = swz >> 5;
    const int qb  = swz & 31;
    const int b   = bh >> 4, h = bh & 15;
    const int tid = threadIdx.x;
    const int w   = tid >> 6;
    const int l   = tid & 63;
    const int q32 = l & 31;
    const int hi  = l >> 5;
    const int qh  = w & 1;                // q-half
    const int kvh = w >> 1;               // kv-half
    const int q0  = qb * QB + qh * 32;

    const __bf16* kbase = ws + KWS_OFF + (size_t)bh * 131072 + kvh * 2048 + l * 8;
    const __bf16* vbase = ws + VWS_OFF + (size_t)bh * 131072 + kvh * 2048 + l * 8;

    // packed-f16 silu constants (SGPR/VGPR per <=1-SGPR-read rule)
    const u32 c_n4   = 0xC400C400u;   // -4.0 x2
    const u32 c_p4   = 0x44004400u;   // +4.0 x2
    const u32 c_mask = 0x7FFF7FFFu;   // |.| x2
    u32 c_a;                          // -0.03125 x2 (VGPR)
    asm("v_mov_b32 %0, 0xA800A800" : "=v"(c_a));
    const u32 c_b    = 0x34003400u;   // 0.25 x2
    const u32 c_h    = 0x38003800u;   // 0.5  x2

    // Q B-frags: lane holds col q = q0+q32, k-dim d = st*16 + hi*8 + j
    bf16x8 qf[4];
#pragma unroll
    for (int st = 0; st < 4; ++st) {
        const float* p = Qg + ((size_t)b * SEQ + q0 + q32) * DM + h * HD + st * 16 + hi * 8;
        float4 a = *(const float4*)p, c = *(const float4*)(p + 4);
        bf16x8 o;
        o[0] = (__bf16)a.x; o[1] = (__bf16)a.y; o[2] = (__bf16)a.z; o[3] = (__bf16)a.w;
        o[4] = (__bf16)c.x; o[5] = (__bf16)c.y; o[6] = (__bf16)c.z; o[7] = (__bf16)c.w;
        qf[st] = o;
    }

    f32x16 accd[2], z16;
#pragma unroll
    for (int r = 0; r < 16; ++r) { accd[0][r] = 0.f; accd[1][r] = 0.f; z16[r] = 0.f; }

    auto tile = [&](int t, bf16x8 (&kCur)[4], bf16x8 (&kNxt)[4]) {
        // V(t): issued now, consumed after QK+silu (~covers L2 latency)
        f16x8 vf[4];
#pragma unroll
        for (int j = 0; j < 4; ++j)
            vf[j] = *(const f16x8*)(vbase + (size_t)t * 4096 + j * 512);
        // K(t+1): full tile of latency ahead
        if (t + 1 < NT) {
#pragma unroll
            for (int st = 0; st < 4; ++st)
                kNxt[st] = *(const bf16x8*)(kbase + (size_t)(t + 1) * 4096 + st * 512);
        }

        // ---- QK^T (A=K half, B=Q)
        __builtin_amdgcn_s_setprio(1);
        f32x16 s = __builtin_amdgcn_mfma_f32_32x32x16_bf16(kCur[0], qf[0], z16, 0, 0, 0);
        s = __builtin_amdgcn_mfma_f32_32x32x16_bf16(kCur[1], qf[1], s, 0, 0, 0);
        s = __builtin_amdgcn_mfma_f32_32x32x16_bf16(kCur[2], qf[2], s, 0, 0, 0);
        s = __builtin_amdgcn_mfma_f32_32x32x16_bf16(kCur[3], qf[3], s, 0, 0, 0);
        __builtin_amdgcn_s_setprio(0);

        // ---- silu, packed f16 (2 elems/instr):
        //      xc = clamp(x,-4,4); p = 0.5 + xc*(0.25 - 0.03125*|xc|); y = x*p
        u32 pw[2][4];
#pragma unroll
        for (int hf = 0; hf < 2; ++hf) {
            u32 Y[4];
#pragma unroll
            for (int pr = 0; pr < 4; ++pr) {
                u32 xpk = __builtin_bit_cast(
                    u32, __builtin_amdgcn_cvt_pkrtz(s[hf * 8 + 2 * pr], s[hf * 8 + 2 * pr + 1]));
                u32 t1, xc, ax, u, p, y;
                asm("v_pk_max_f16 %0, %1, %2" : "=v"(t1) : "v"(xpk), "s"(c_n4));
                asm("v_pk_min_f16 %0, %1, %2" : "=v"(xc) : "v"(t1), "s"(c_p4));
                asm("v_and_b32 %0, %1, %2"    : "=v"(ax) : "s"(c_mask), "v"(xc));
                asm("v_pk_fma_f16 %0, %1, %2, %3" : "=v"(u) : "v"(ax), "v"(c_a), "s"(c_b));
                asm("v_pk_fma_f16 %0, %1, %2, %3" : "=v"(p) : "v"(xc), "v"(u), "s"(c_h));
                asm("v_pk_mul_f16 %0, %1, %2" : "=v"(y) : "v"(xpk), "v"(p));
                Y[pr] = y;
            }
            // cross-half exchange: frag words [Y0, Y1, Y2, Y3] after swaps
            asm("v_permlane32_swap_b32 %0, %1" : "+v"(Y[0]), "+v"(Y[2]));
            asm("v_permlane32_swap_b32 %0, %1" : "+v"(Y[1]), "+v"(Y[3]));
            pw[hf][0] = Y[0]; pw[hf][1] = Y[1]; pw[hf][2] = Y[2]; pw[hf][3] = Y[3];
        }

        // ---- out += P * V   (f16 MFMA; P f16 frags, V f16 regs)
        union { u32 u[4]; f16x8 v; } p0, p1;
        p0.u[0] = pw[0][0]; p0.u[1] = pw[0][1]; p0.u[2] = pw[0][2]; p0.u[3] = pw[0][3];
        p1.u[0] = pw[1][0]; p1.u[1] = pw[1][1]; p1.u[2] = pw[1][2]; p1.u[3] = pw[1][3];
        __builtin_amdgcn_s_setprio(1);
        accd[0] = __builtin_amdgcn_mfma_f32_32x32x16_f16(p0.v, vf[0], accd[0], 0, 0, 0);
        accd[0] = __builtin_amdgcn_mfma_f32_32x32x16_f16(p1.v, vf[1], accd[0], 0, 0, 0);
        accd[1] = __builtin_amdgcn_mfma_f32_32x32x16_f16(p0.v, vf[2], accd[1], 0, 0, 0);
        accd[1] = __builtin_amdgcn_mfma_f32_32x32x16_f16(p1.v, vf[3], accd[1], 0, 0, 0);
        __builtin_amdgcn_s_setprio(0);
    };

    bf16x8 kA[4], kB[4];
#pragma unroll
    for (int st = 0; st < 4; ++st)
        kA[st] = *(const bf16x8*)(kbase + st * 512);

    for (int t = 0; t < NT; t += 2) {
        tile(t,     kA, kB);
        tile(t + 1, kB, kA);
    }

    // ---- kv-half reduction via LDS (lane-contiguous, conflict-free)
    if (w >= 2) {                                    // kvh==1 writes
#pragma unroll
        for (int db = 0; db < 2; ++db)
#pragma unroll
            for (int r = 0; r < 16; ++r)
                red[(db * 16 + r) * 128 + qh * 64 + l] = accd[db][r];
    }
    __syncthreads();
    if (w < 2) {                                     // kvh==0 adds + stores
#pragma unroll
        for (int db = 0; db < 2; ++db)
#pragma unroll
            for (int r = 0; r < 16; ++r)
                accd[db][r] += red[(db * 16 + r) * 128 + qh * 64 + l];
        // D layout: row q = m*8 + r + hi*4, col d = db*32 + q32 (coalesced)
        float* op = Og + ((size_t)b * SEQ + q0) * DM + h * HD;
#pragma unroll
        for (int db = 0; db < 2; ++db)
#pragma unroll
            for (int m = 0; m < 4; ++m)
#pragma unroll
                for (int r = 0; r < 4; ++r)
                    op[(size_t)(m * 8 + r + hi * 4) * DM + db * 32 + q32] = accd[db][m * 4 + r];
    }
}

extern "C" void kernel_launch(void* const* d_in, const int* in_sizes, int n_in,
                              void* d_out, int out_size, void* d_ws, size_t ws_size,
                              hipStream_t stream) {
    const float* v = (const float*)d_in[0];
    const float* k = (const float*)d_in[1];
    const float* q = (const float*)d_in[2];
    float* out = (float*)d_out;
    __bf16* ws = (__bf16*)d_ws;
    (void)in_sizes; (void)n_in; (void)out_size; (void)ws_size;

    psa_prep<<<dim3(4096), dim3(256), 0, stream>>>(v, k, ws);
    psa_main<<<dim3(BH * (SEQ / QB)), dim3(256), 0, stream>>>(ws, q, out);
}